// Round 6
// baseline (1193.895 us; speedup 1.0000x reference)
//
#include <hip/hip_runtime.h>
#include <hip/hip_bf16.h>

#define NN 100000
#define NE 1250000
#define DD 64
#define RR 16
#define NTILE 6250            // NN/16 dst-tiles
#define NBLK_SCAN 391         // ceil(NN/256)
#define SST 68                // padded LDS stride (floats) for S rows

typedef __attribute__((ext_vector_type(8))) short s16x8;
typedef __attribute__((ext_vector_type(4))) float f32x4;

static __device__ __forceinline__ unsigned short f2bf(float v) {
    __hip_bfloat16 h = __float2bfloat16(v);
    return __builtin_bit_cast(unsigned short, h);
}
static __device__ __forceinline__ float bf2f(unsigned short u) {
    unsigned int w = ((unsigned int)u) << 16;
    return __builtin_bit_cast(float, w);
}
static __device__ __forceinline__ unsigned int pack2(float a, float b) {
    return ((unsigned int)f2bf(b) << 16) | (unsigned int)f2bf(a);
}

// ---------------- sort edges by dst (counting sort, NN bins) ----------------

__global__ void hist_dst(const int* __restrict__ dst, int* __restrict__ cnt) {
    int e = blockIdx.x * 256 + threadIdx.x;
    if (e < NE) atomicAdd(&cnt[dst[e]], 1);
}

__global__ __launch_bounds__(256) void scan1(const int* __restrict__ cnt,
                                             int* __restrict__ rp, int* __restrict__ part) {
    __shared__ int s[256];
    int i = blockIdx.x * 256 + threadIdx.x;
    int v = (i < NN) ? cnt[i] : 0;
    s[threadIdx.x] = v;
    __syncthreads();
    for (int off = 1; off < 256; off <<= 1) {
        int t = (threadIdx.x >= off) ? s[threadIdx.x - off] : 0;
        __syncthreads();
        s[threadIdx.x] += t;
        __syncthreads();
    }
    if (i < NN) rp[i] = s[threadIdx.x] - v;           // block-local exclusive
    if (threadIdx.x == 255) part[blockIdx.x] = s[255];
}

__global__ void scan2(int* __restrict__ part, int* __restrict__ rp) {
    __shared__ int s[NBLK_SCAN];
    if (threadIdx.x < NBLK_SCAN) s[threadIdx.x] = part[threadIdx.x];
    __syncthreads();
    if (threadIdx.x == 0) {
        int acc = 0;
        for (int b = 0; b < NBLK_SCAN; ++b) { int t = s[b]; s[b] = acc; acc += t; }
        rp[NN] = NE;
    }
    __syncthreads();
    if (threadIdx.x < NBLK_SCAN) part[threadIdx.x] = s[threadIdx.x];
}

__global__ void scan3(int* __restrict__ rp, const int* __restrict__ part, int* __restrict__ cur) {
    int i = blockIdx.x * 256 + threadIdx.x;
    if (i < NN) {
        int v = rp[i] + part[blockIdx.x];
        rp[i] = v;
        cur[i] = v;
    }
}

// ep[p] = src | rel<<17 | (dst&15)<<21   (single 4B store per edge)
__global__ void scatter_pack(const int* __restrict__ src, const int* __restrict__ dst,
                             const int* __restrict__ et, int* __restrict__ cur,
                             unsigned int* __restrict__ ep) {
    int e = blockIdx.x * 256 + threadIdx.x;
    if (e >= NE) return;
    int d = dst[e];
    int p = atomicAdd(&cur[d], 1);
    ep[p] = (unsigned int)src[e] | ((unsigned int)et[e] << 17)
          | ((unsigned int)(d & 15) << 21);
}

// ---------------- precision prep ----------------

// wt[l][p][o][d] = bf16( (p<16 ? W_l[p] : sw_l)[d][o] )   (A-operand layout, m=o, k=d)
__global__ void prep_w2(const float* __restrict__ W1, const float* __restrict__ sw1,
                        const float* __restrict__ W2, const float* __restrict__ sw2,
                        unsigned short* __restrict__ wt) {
    int i = blockIdx.x * 256 + threadIdx.x;
    if (i >= 2 * 17 * DD * DD) return;
    int d = i & 63;
    int o = (i >> 6) & 63;
    int p = (i >> 12) % 17;
    int l = i / (17 * DD * DD);
    const float* srcp;
    if (p < 16) srcp = (l ? W2 : W1) + p * DD * DD;
    else        srcp = (l ? sw2 : sw1);
    wt[i] = f2bf(srcp[d * DD + o]);
}

__global__ void prep_x2(const float* __restrict__ x, unsigned short* __restrict__ xb) {
    int i = blockIdx.x * blockDim.x + threadIdx.x;
    if (i < NN * DD) xb[i] = f2bf(x[i]);
}

// ---------------- fused layer kernel ----------------
// Block = 16 dsts. Input-space aggregation: S[rel][dstloc][ch] += x[src],
// then per-rel MFMA (A = W_r^T from global, B = bf16(S)) accumulating
// C[o][dst] in registers across all 16 rels + self plane. Epilogue fuses
// bias (+residual) + relu, emits bf16 (layer1) or fp32 (layer2).
__global__ __launch_bounds__(256) void fused_layer(
    const unsigned short* __restrict__ xb,   // [N][64] bf16 layer input
    const unsigned short* __restrict__ wt,   // [17][64][64] bf16 (o-major, d inner)
    const int* __restrict__ rp,              // [N+1] CSR by dst
    const unsigned int* __restrict__ ep,     // [E] packed {src,rel,dstloc}
    const float* __restrict__ bias,
    const float* __restrict__ xres,          // fp32 residual or nullptr
    unsigned short* __restrict__ outb,       // bf16 out (layer1) or nullptr
    float* __restrict__ outf)                // fp32 out (layer2) or nullptr
{
    __shared__ float S[8 * 16 * SST];        // 34816 B
    const int n0   = blockIdx.x * 16;
    const int wid  = threadIdx.x >> 6;
    const int lane = threadIdx.x & 63;
    const int c = lane & 15;                 // MFMA col: dstloc (MFMA phase) / tile row
    const int q = lane >> 4;
    const int h  = lane >> 5;                // half-wave edge stream
    const int ol = lane & 31;                // channel pair: ch = 2*ol, 2*ol+1

    const int e0 = rp[n0];
    const int e1 = rp[n0 + 16];
    const unsigned int* xb32 = (const unsigned int*)xb;

    f32x4 acc = {0.f, 0.f, 0.f, 0.f};

    for (int pass = 0; pass < 2; ++pass) {
        const int rbase = pass * 8;
        // zero S
        for (int i = threadIdx.x; i < 8 * 16 * SST; i += 256) S[i] = 0.f;
        __syncthreads();

        // accumulate edges of this pass's 8 rels (8 edges per wave per batch)
        for (int base = e0 + wid * 8; base < e1; base += 32) {
            unsigned int w[4];
            int act[4];
            #pragma unroll
            for (int j = 0; j < 4; ++j) {
                int e = base + 2 * j + h;
                act[j] = (e < e1);
                w[j] = act[j] ? ep[e] : 0u;
            }
            float v0[4], v1[4];
            #pragma unroll
            for (int j = 0; j < 4; ++j) {
                int rel = (w[j] >> 17) & 15;
                act[j] = act[j] && (rel >= rbase) && (rel < rbase + 8);
                if (act[j]) {
                    int srcn = w[j] & 0x1FFFF;
                    unsigned int u = xb32[(size_t)srcn * 32 + ol];
                    v0[j] = bf2f((unsigned short)u);
                    v1[j] = bf2f((unsigned short)(u >> 16));
                }
            }
            #pragma unroll
            for (int j = 0; j < 4; ++j) {
                if (act[j]) {
                    int r8 = ((w[j] >> 17) & 15) - rbase;
                    int dl = (w[j] >> 21) & 15;
                    float* sp = &S[(r8 * 16 + dl) * SST + ol * 2];
                    atomicAdd(sp,     v0[j]);
                    atomicAdd(sp + 1, v1[j]);
                }
            }
        }
        __syncthreads();

        // MFMA: wave wid = o-block; accumulate over this pass's 8 rels
        for (int rr = 0; rr < 8; ++rr) {
            const int r = rbase + rr;
            const float* srow = &S[(rr * 16 + c) * SST + q * 8];
            const f32x4* s4 = (const f32x4*)srow;
            f32x4 f0 = s4[0], f1 = s4[1];          // k = q*8 + 0..7
            const f32x4* s4b = (const f32x4*)(srow + 32);
            f32x4 f2 = s4b[0], f3 = s4b[1];        // k = 32 + q*8 + 0..7
            s16x8 b0, b1;
            #pragma unroll
            for (int j = 0; j < 4; ++j) {
                b0[j]     = (short)f2bf(f0[j]);
                b0[j + 4] = (short)f2bf(f1[j]);
                b1[j]     = (short)f2bf(f2[j]);
                b1[j + 4] = (short)f2bf(f3[j]);
            }
            const unsigned short* wrow = wt + r * (DD * DD) + (wid * 16 + c) * DD + q * 8;
            s16x8 a0 = *(const s16x8*)(wrow);
            s16x8 a1 = *(const s16x8*)(wrow + 32);
            acc = __builtin_amdgcn_mfma_f32_16x16x32_bf16(a0, b0, acc, 0, 0, 0);
            acc = __builtin_amdgcn_mfma_f32_16x16x32_bf16(a1, b1, acc, 0, 0, 0);
        }
        __syncthreads();   // protect S before next pass's zeroing
    }

    // self plane (p=16): B = x rows of this tile (sequential)
    {
        const unsigned short* xrow = xb + (size_t)(n0 + c) * DD + q * 8;
        s16x8 b0 = *(const s16x8*)(xrow);
        s16x8 b1 = *(const s16x8*)(xrow + 32);
        const unsigned short* wrow = wt + 16 * (DD * DD) + (wid * 16 + c) * DD + q * 8;
        s16x8 a0 = *(const s16x8*)(wrow);
        s16x8 a1 = *(const s16x8*)(wrow + 32);
        acc = __builtin_amdgcn_mfma_f32_16x16x32_bf16(a0, b0, acc, 0, 0, 0);
        acc = __builtin_amdgcn_mfma_f32_16x16x32_bf16(a1, b1, acc, 0, 0, 0);
    }

    // epilogue: lane (c,q) holds o = wid*16 + q*4 + v for dst n0+c
    const int n = n0 + c;
    const int obase = wid * 16 + q * 4;
    const float4 bv = *(const float4*)(bias + obase);
    acc[0] += bv.x; acc[1] += bv.y; acc[2] += bv.z; acc[3] += bv.w;
    if (xres) {
        const float4 rv = *(const float4*)(xres + (size_t)n * DD + obase);
        acc[0] += rv.x; acc[1] += rv.y; acc[2] += rv.z; acc[3] += rv.w;
    }
    acc[0] = fmaxf(acc[0], 0.f);
    acc[1] = fmaxf(acc[1], 0.f);
    acc[2] = fmaxf(acc[2], 0.f);
    acc[3] = fmaxf(acc[3], 0.f);

    if (outb) {
        uint2 pk;
        pk.x = pack2(acc[0], acc[1]);
        pk.y = pack2(acc[2], acc[3]);
        *(uint2*)(outb + (size_t)n * DD + obase) = pk;
    }
    if (outf) {
        float4 v = {acc[0], acc[1], acc[2], acc[3]};
        *(float4*)(outf + (size_t)n * DD + obase) = v;
    }
}

// ================= launch =================

extern "C" void kernel_launch(void* const* d_in, const int* in_sizes, int n_in,
                              void* d_out, int out_size, void* d_ws, size_t ws_size,
                              hipStream_t stream)
{
    (void)in_sizes; (void)n_in; (void)out_size; (void)ws_size;
    const float* x    = (const float*)d_in[0];
    const int*   ei   = (const int*)d_in[1];
    const int*   et   = (const int*)d_in[2];
    const float* W1   = (const float*)d_in[3];
    const float* sw1  = (const float*)d_in[4];
    const float* b1   = (const float*)d_in[5];
    const float* W2   = (const float*)d_in[6];
    const float* sw2  = (const float*)d_in[7];
    const float* b2   = (const float*)d_in[8];
    float* out = (float*)d_out;

    const int* srcA = ei;
    const int* dstA = ei + NE;

    char* ws = (char*)d_ws;
    unsigned short* xb   = (unsigned short*)(ws);                 // 12,800,000
    unsigned short* h1b  = (unsigned short*)(ws + 12800000);      // 12,800,000
    unsigned short* wt2  = (unsigned short*)(ws + 25600000);      //    278,528
    unsigned int*   ep   = (unsigned int*)(ws + 25878528);        //  5,000,000
    int*            rp   = (int*)(ws + 30878528);                 //    400,004
    int*            cnt  = (int*)(ws + 31278544);                 //    400,000
    int*            cur  = (int*)(ws + 31678544);                 //    400,000
    int*            part = (int*)(ws + 32078544);                 //      1,600

    const int NB_E    = (NE + 255) / 256;        // 4883
    const int NB_ELEM = (NN * DD + 255) / 256;   // 25000
    const int WPL = 17 * DD * DD;                // wt2 per-layer stride

    // ---- sort edges by dst (once; reused by both layers) ----
    hipMemsetAsync(cnt, 0, NN * sizeof(int), stream);
    hist_dst<<<NB_E, 256, 0, stream>>>(dstA, cnt);
    scan1<<<NBLK_SCAN, 256, 0, stream>>>(cnt, rp, part);
    scan2<<<1, 512, 0, stream>>>(part, rp);
    scan3<<<NBLK_SCAN, 256, 0, stream>>>(rp, part, cur);
    scatter_pack<<<NB_E, 256, 0, stream>>>(srcA, dstA, et, cur, ep);

    // ---- precision prep ----
    prep_w2<<<(2 * 17 * DD * DD + 255) / 256, 256, 0, stream>>>(W1, sw1, W2, sw2, wt2);
    prep_x2<<<NB_ELEM, 256, 0, stream>>>(x, xb);

    // ---- layer 1 (residual) ----
    fused_layer<<<NTILE, 256, 0, stream>>>(xb, wt2, rp, ep, b1, x, h1b, nullptr);
    // ---- layer 2 (no residual) ----
    fused_layer<<<NTILE, 256, 0, stream>>>(h1b, wt2 + WPL, rp, ep, b2, nullptr, nullptr, out);
}

// Round 8
// 535.476 us; speedup vs baseline: 2.2296x; 2.2296x over previous
//
#include <hip/hip_runtime.h>
#include <hip/hip_bf16.h>

#define NN 100000
#define NE 1250000
#define DD 64
#define RR 16
#define NP 17            // 16 relations + self plane
#define NTILE 6250       // NN/16
#define NBLK_SCAN 391    // ceil(NN/256)
#define LST 68           // LDS row stride in ushorts (136 B, 8B-aligned)

typedef __attribute__((ext_vector_type(8))) short s16x8;
typedef __attribute__((ext_vector_type(4))) float f32x4;

static __device__ __forceinline__ unsigned short f2bf(float v) {
    __hip_bfloat16 h = __float2bfloat16(v);
    return __builtin_bit_cast(unsigned short, h);
}
static __device__ __forceinline__ float bf2f(unsigned short u) {
    unsigned int w = ((unsigned int)u) << 16;
    return __builtin_bit_cast(float, w);
}
static __device__ __forceinline__ unsigned int pack2(float a, float b) {
    return ((unsigned int)f2bf(b) << 16) | (unsigned int)f2bf(a);
}

// ---------------- sort edges by dst (counting sort, NN bins) ----------------

__global__ void hist_dst(const int* __restrict__ dst, int* __restrict__ cnt) {
    int e = blockIdx.x * 256 + threadIdx.x;
    if (e < NE) atomicAdd(&cnt[dst[e]], 1);
}

__global__ __launch_bounds__(256) void scan1(const int* __restrict__ cnt,
                                             int* __restrict__ rp, int* __restrict__ part) {
    __shared__ int s[256];
    int i = blockIdx.x * 256 + threadIdx.x;
    int v = (i < NN) ? cnt[i] : 0;
    s[threadIdx.x] = v;
    __syncthreads();
    for (int off = 1; off < 256; off <<= 1) {
        int t = (threadIdx.x >= off) ? s[threadIdx.x - off] : 0;
        __syncthreads();
        s[threadIdx.x] += t;
        __syncthreads();
    }
    if (i < NN) rp[i] = s[threadIdx.x] - v;           // exclusive
    if (threadIdx.x == 255) part[blockIdx.x] = s[255];
}

__global__ void scan2(int* __restrict__ part, int* __restrict__ rp) {
    __shared__ int s[NBLK_SCAN];
    if (threadIdx.x < NBLK_SCAN) s[threadIdx.x] = part[threadIdx.x];
    __syncthreads();
    if (threadIdx.x == 0) {
        int acc = 0;
        for (int b = 0; b < NBLK_SCAN; ++b) { int t = s[b]; s[b] = acc; acc += t; }
        rp[NN] = NE;
    }
    __syncthreads();
    if (threadIdx.x < NBLK_SCAN) part[threadIdx.x] = s[threadIdx.x];
}

__global__ void scan3(int* __restrict__ rp, const int* __restrict__ part, int* __restrict__ cur) {
    int i = blockIdx.x * 256 + threadIdx.x;
    if (i < NN) {
        int v = rp[i] + part[blockIdx.x];
        rp[i] = v;
        cur[i] = v;
    }
}

// sg[p] = rel*NN + src   (row index into the [17*N] table)
__global__ void scatter_dst(const int* __restrict__ src, const int* __restrict__ dst,
                            const int* __restrict__ et, int* __restrict__ cur,
                            int* __restrict__ sg) {
    int e = blockIdx.x * 256 + threadIdx.x;
    if (e >= NE) return;
    int p = atomicAdd(&cur[dst[e]], 1);
    sg[p] = et[e] * NN + src[e];
}

// ---------------- precision prep ----------------

// wt2[l][p][o][d] = bf16( (p<16 ? W_l[p] : sw_l)[d][o] )  (A-operand: m=o, k=d)
__global__ void prep_w2(const float* __restrict__ W1, const float* __restrict__ sw1,
                        const float* __restrict__ W2, const float* __restrict__ sw2,
                        unsigned short* __restrict__ wt) {
    int i = blockIdx.x * 256 + threadIdx.x;
    if (i >= 2 * NP * DD * DD) return;
    int d = i & 63;
    int o = (i >> 6) & 63;
    int p = (i >> 12) % NP;
    int l = i / (NP * DD * DD);
    const float* srcp;
    if (p < 16) srcp = (l ? W2 : W1) + p * DD * DD;
    else        srcp = (l ? sw2 : sw1);
    wt[i] = f2bf(srcp[d * DD + o]);
}

__global__ void prep_x2(const float* __restrict__ x, unsigned short* __restrict__ xb) {
    int i = blockIdx.x * blockDim.x + threadIdx.x;
    if (i < NN * DD) xb[i] = f2bf(x[i]);
}

// ---------------- kernel A: bf16 table with full-line stores ----------------
// Transposed MFMA (C: row=o in regs, col=node in lanes). Epilogue stages the
// 16-node x 128B tile through per-wave LDS, then stores 512B-contiguous per
// instruction (full 64B lines) instead of 32B half-line segments.
__global__ __launch_bounds__(256) void xw_kernel(
    const unsigned short* __restrict__ xb,   // [N][64] bf16 (B: k=d, n=node)
    const unsigned short* __restrict__ wt,   // [17][64][64] bf16 (A: m=o, k=d)
    unsigned short* __restrict__ tab)        // [17][N][64] bf16
{
    __shared__ unsigned short lds[4][16 * LST];
    const int wid  = threadIdx.x >> 6;
    const int lane = threadIdx.x & 63;
    const int c = lane & 15;       // node within tile
    const int q = lane >> 4;
    const int t = blockIdx.x * 4 + wid;
    if (t >= NTILE) return;
    const int n0 = t * 16;
    const int p0 = blockIdx.y * 4;
    const int p1 = min(p0 + 4, NP);

    const unsigned short* xrow = xb + (size_t)(n0 + c) * DD + q * 8;
    s16x8 b0 = *(const s16x8*)(xrow);
    s16x8 b1 = *(const s16x8*)(xrow + 32);

    unsigned short* lw = lds[wid];

    for (int p = p0; p < p1; ++p) {
        const unsigned short* wp = wt + p * (DD * DD);
        #pragma unroll
        for (int nb = 0; nb < 4; ++nb) {
            const unsigned short* wrow = wp + (nb * 16 + c) * DD + q * 8;
            s16x8 a0 = *(const s16x8*)(wrow);
            s16x8 a1 = *(const s16x8*)(wrow + 32);
            f32x4 acc = {0.f, 0.f, 0.f, 0.f};
            acc = __builtin_amdgcn_mfma_f32_16x16x32_bf16(a0, b0, acc, 0, 0, 0);
            acc = __builtin_amdgcn_mfma_f32_16x16x32_bf16(a1, b1, acc, 0, 0, 0);
            // lane (c,q) holds channels nb*16+q*4..+3 of node c
            uint2 pk;
            pk.x = pack2(acc[0], acc[1]);
            pk.y = pack2(acc[2], acc[3]);
            *(uint2*)&lw[c * LST + nb * 16 + q * 4] = pk;
        }
        // drain LDS tile -> contiguous global stores (512B per instruction)
        unsigned short* gbase = tab + ((size_t)p * NN + n0) * DD;
        #pragma unroll
        for (int j = 0; j < 4; ++j) {
            int i8 = lane + 64 * j;          // 8B piece index within 2KB tile
            int node = i8 >> 4;
            int k8 = i8 & 15;
            uint2 v = *(const uint2*)&lw[node * LST + k8 * 4];
            *(uint2*)(gbase + (size_t)i8 * 4) = v;
        }
    }
}

// ---------------- kernel B: per-dst segment sum ----------------
// Half-wave per node (2 nodes/wave): 32 lanes x 4B = full 128B row per gather,
// 4-deep unroll -> 8 independent row gathers in flight per wave. Self/bias/
// (residual) init before the loop; relu + store in epilogue. No shuffles.
__global__ __launch_bounds__(256) void agg_kernel(
    const unsigned short* __restrict__ tab,  // [17*N][64] bf16
    const int* __restrict__ rp,              // [N+1]
    const int* __restrict__ sg,              // [E] row = rel*NN+src
    const float* __restrict__ bias,
    const float* __restrict__ xres,          // fp32 residual or nullptr
    unsigned short* __restrict__ outb,       // bf16 out (layer 1) or nullptr
    float* __restrict__ outf)                // fp32 out (layer 2) or nullptr
{
    const int hw = threadIdx.x >> 5;         // half-wave 0..7
    const int ll = threadIdx.x & 31;         // channel pair: ch = 2*ll, 2*ll+1
    const int n = blockIdx.x * 8 + hw;       // 12500*8 == NN exactly
    const unsigned int* t32 = (const unsigned int*)tab;

    // init: self plane + bias (+ residual)
    unsigned int us = t32[((size_t)16 * NN + n) * 32 + ll];
    const float2 bv = *(const float2*)(bias + ll * 2);
    float a0 = bv.x + bf2f((unsigned short)us);
    float a1 = bv.y + bf2f((unsigned short)(us >> 16));
    if (xres) {
        const float2 rv = *(const float2*)(xres + (size_t)n * DD + ll * 2);
        a0 += rv.x; a1 += rv.y;
    }

    int e = rp[n];
    const int e1 = rp[n + 1];
    for (; e + 4 <= e1; e += 4) {
        int r0 = sg[e], r1 = sg[e + 1], r2 = sg[e + 2], r3 = sg[e + 3];
        unsigned int u0 = t32[(size_t)r0 * 32 + ll];
        unsigned int u1 = t32[(size_t)r1 * 32 + ll];
        unsigned int u2 = t32[(size_t)r2 * 32 + ll];
        unsigned int u3 = t32[(size_t)r3 * 32 + ll];
        a0 += bf2f((unsigned short)u0) + bf2f((unsigned short)u1);
        a1 += bf2f((unsigned short)(u0 >> 16)) + bf2f((unsigned short)(u1 >> 16));
        a0 += bf2f((unsigned short)u2) + bf2f((unsigned short)u3);
        a1 += bf2f((unsigned short)(u2 >> 16)) + bf2f((unsigned short)(u3 >> 16));
    }
    {   // predicated tail (0..3 edges), loads kept independent
        const int m = e1 - e;
        int rA = (m > 0) ? sg[e]     : -1;
        int rB = (m > 1) ? sg[e + 1] : -1;
        int rC = (m > 2) ? sg[e + 2] : -1;
        if (rA >= 0) {
            unsigned int u = t32[(size_t)rA * 32 + ll];
            a0 += bf2f((unsigned short)u); a1 += bf2f((unsigned short)(u >> 16));
        }
        if (rB >= 0) {
            unsigned int u = t32[(size_t)rB * 32 + ll];
            a0 += bf2f((unsigned short)u); a1 += bf2f((unsigned short)(u >> 16));
        }
        if (rC >= 0) {
            unsigned int u = t32[(size_t)rC * 32 + ll];
            a0 += bf2f((unsigned short)u); a1 += bf2f((unsigned short)(u >> 16));
        }
    }

    a0 = fmaxf(a0, 0.f);
    a1 = fmaxf(a1, 0.f);
    if (outb)
        *(unsigned int*)(outb + (size_t)n * DD + ll * 2) = pack2(a0, a1);
    if (outf) {
        float2 v = {a0, a1};
        *(float2*)(outf + (size_t)n * DD + ll * 2) = v;
    }
}

// ================= launch =================

extern "C" void kernel_launch(void* const* d_in, const int* in_sizes, int n_in,
                              void* d_out, int out_size, void* d_ws, size_t ws_size,
                              hipStream_t stream)
{
    (void)in_sizes; (void)n_in; (void)out_size; (void)ws_size;
    const float* x    = (const float*)d_in[0];
    const int*   ei   = (const int*)d_in[1];
    const int*   et   = (const int*)d_in[2];
    const float* W1   = (const float*)d_in[3];
    const float* sw1  = (const float*)d_in[4];
    const float* b1   = (const float*)d_in[5];
    const float* W2   = (const float*)d_in[6];
    const float* sw2  = (const float*)d_in[7];
    const float* b2   = (const float*)d_in[8];
    float* out = (float*)d_out;

    const int* srcA = ei;
    const int* dstA = ei + NE;

    char* ws = (char*)d_ws;
    unsigned short* tab  = (unsigned short*)(ws);                 // 217,600,000
    unsigned short* xb   = (unsigned short*)(ws + 217600000);     //  12,800,000
    unsigned short* h1b  = (unsigned short*)(ws + 230400000);     //  12,800,000
    unsigned short* wt2  = (unsigned short*)(ws + 243200000);     //     278,528
    int* sg   = (int*)(ws + 243478528);                           //   5,000,000
    int* rp   = (int*)(ws + 248478528);                           //     400,004
    int* cur  = (int*)(ws + 248878544);                           //     400,000
    int* cnt  = (int*)(ws + 249278544);                           //     400,000
    int* part = (int*)(ws + 249678544);                           //       1,600

    const int NB_E    = (NE + 255) / 256;        // 4883
    const int NB_ELEM = (NN * DD + 255) / 256;   // 25000

    // sort edges by dst (once; reused by both layers)
    hipMemsetAsync(cnt, 0, NN * sizeof(int), stream);
    hist_dst<<<NB_E, 256, 0, stream>>>(dstA, cnt);
    scan1<<<NBLK_SCAN, 256, 0, stream>>>(cnt, rp, part);
    scan2<<<1, 512, 0, stream>>>(part, rp);
    scan3<<<NBLK_SCAN, 256, 0, stream>>>(rp, part, cur);
    scatter_dst<<<NB_E, 256, 0, stream>>>(srcA, dstA, et, cur, sg);

    // precision prep
    prep_w2<<<(2 * NP * DD * DD + 255) / 256, 256, 0, stream>>>(W1, sw1, W2, sw2, wt2);
    prep_x2<<<NB_ELEM, 256, 0, stream>>>(x, xb);

    const int NB_XW  = (NTILE + 3) / 4;          // 1563
    const int NB_AGG = NN / 8;                   // 12500
    const int WPL = NP * DD * DD;                // wt2 per-layer stride

    // ---- layer 1 (residual) ----
    xw_kernel<<<dim3(NB_XW, 5), 256, 0, stream>>>(xb, wt2, tab);
    agg_kernel<<<NB_AGG, 256, 0, stream>>>(tab, rp, sg, b1, x, h1b, nullptr);

    // ---- layer 2 (no residual) ----
    xw_kernel<<<dim3(NB_XW, 5), 256, 0, stream>>>(h1b, wt2 + WPL, tab);
    agg_kernel<<<NB_AGG, 256, 0, stream>>>(tab, rp, sg, b2, nullptr, nullptr, out);
}